// Round 14
// baseline (264.755 us; speedup 1.0000x reference)
//
#include <hip/hip_runtime.h>
#include <hip/hip_bf16.h>

// Attention4D MI355X round 25 (= r24 resubmit; audited, infra-failure suspected):
//  - r24 audit: LDS staging bounds (max 16384 <= 28672), swizzle write/read
//    algebra consistent, barriers uniform, ot max offset == buffer size,
//    workspace byte-identical to proven r14..r23. No defect found; r10/r15
//    sessions showed the same infra failure mode with sound code.
//  - k_attn2 phase-5 epilogue: O-tile staged into dead S (quad-XOR bank
//    swizzle), then 4 coalesced 16B stores/thread (64 lanes = 1KB/inst);
//    was 32 scalar 2B stores/thread with partial-line eviction (slow-session
//    WRITE 29.3 vs 26.9MB). Phases 1-4 + MFMA loop byte-identical to r14.
//  - Everything else byte-identical to r23 (257.4us slow-session):
//    coalesced stores in k_qkv/k_proj/k_vtdw, XCD-aware grids, per-plane
//    k_vtdw.
// B=64, DIM=384, N=196 (14x14), NH=8, KD=32, DV=128.

#define RES   14
#define NSP   196
#define NHD   8
#define KDIM  32
#define DVV   128
#define DIM   384
#define NQK   256
#define SCALE 0.17677669529663687f
#define SROW  224    // LDS score row stride (u16); 448B ≡ bank16: 2-way, free
#define PROW  136    // k_vtdw plane row stride (u16); 272B: 16B-aligned, +4 banks
#define NSTRIP 13    // 13 x 16 = 208 >= 196

typedef __attribute__((ext_vector_type(8))) short bf16x8;
typedef __attribute__((ext_vector_type(4))) float f32x4;
typedef __attribute__((ext_vector_type(4))) unsigned short u16x4;
typedef unsigned short u16;
typedef unsigned int u32;

__device__ __forceinline__ u16 f2b(float f) {
    union { __hip_bfloat16 b; u16 u; } c; c.b = __float2bfloat16(f); return c.u;
}
__device__ __forceinline__ float b2f(u16 u) {
    union { __hip_bfloat16 b; u16 u; } c; c.u = u; return __bfloat162float(c.b);
}

// async global->LDS, 16B per lane; LDS dest = wave-uniform base + lane*16
__device__ __forceinline__ void gld16(const void* g, void* l) {
    __builtin_amdgcn_global_load_lds(
        (__attribute__((address_space(1))) void*)(unsigned long long)(const char*)g,
        (__attribute__((address_space(3))) void*)l, 16, 0, 0);
}

// ---- 128x128 bf16 MFMA GEMM core, BK=64 (two BK=32 sub-tiles / barrier) ----
__device__ __forceinline__ void gemm128_bk64(const char* Aseg, long rbA,
                                             const char* Bseg, long rbB, int kIters,
                                             u16* A_lds, u16* B_lds, f32x4 acc[4][4])
{
    const int tid  = threadIdx.x;
    const int wid  = tid >> 6;
    const int lane = tid & 63;
    const int lrow = lane >> 2;
    const int lcb  = (lane & 3) << 4;
    const int r0   = wid * 32;
    const int wm   = (wid & 1) * 64, wn = (wid >> 1) * 64;
    const int l15  = lane & 15, lq8 = (lane >> 4) * 8;

    #pragma unroll
    for (int i = 0; i < 4; ++i)
        #pragma unroll
        for (int j = 0; j < 4; ++j) acc[i][j] = (f32x4){0.f, 0.f, 0.f, 0.f};

    const char* ap0 = Aseg + (long)(r0 + lrow) * rbA + lcb;
    const char* ap1 = ap0 + 16 * rbA;
    const char* bp0 = Bseg + (long)(r0 + lrow) * rbB + lcb;
    const char* bp1 = bp0 + 16 * rbB;
    u16* la0 = A_lds + r0 * 32;
    u16* la1 = la0 + 512;
    u16* lb0 = B_lds + r0 * 32;
    u16* lb1 = lb0 + 512;

    for (int kk = 0; kk < kIters; ++kk) {
        gld16(ap0, la0);        gld16(ap1, la1);
        gld16(bp0, lb0);        gld16(bp1, lb1);
        gld16(ap0 + 64, la0 + 4096); gld16(ap1 + 64, la1 + 4096);
        gld16(bp0 + 64, lb0 + 4096); gld16(bp1 + 64, lb1 + 4096);
        ap0 += 128; ap1 += 128; bp0 += 128; bp1 += 128;
        __syncthreads();
        #pragma unroll
        for (int s = 0; s < 2; ++s) {
            bf16x8 af[4], bfr[4];
            #pragma unroll
            for (int i = 0; i < 4; ++i)
                af[i] = *(const bf16x8*)&A_lds[s * 4096 + (wm + i * 16 + l15) * 32 + lq8];
            #pragma unroll
            for (int j = 0; j < 4; ++j)
                bfr[j] = *(const bf16x8*)&B_lds[s * 4096 + (wn + j * 16 + l15) * 32 + lq8];
            #pragma unroll
            for (int i = 0; i < 4; ++i)
                #pragma unroll
                for (int j = 0; j < 4; ++j)
                    acc[i][j] = __builtin_amdgcn_mfma_f32_16x16x32_bf16(
                        af[i], bfr[j], acc[i][j], 0, 0, 0);
        }
        __syncthreads();
    }
}

// ---------------- prep (merged): weights + biasmix + wpack + x transpose ----
// blocks [0,960): float4-vectorized weight conversions (4 elems/thread);
// 960: biasmix; [961,997): wpack; [997,6373): x transpose.
__global__ __launch_bounds__(256) void k_prep(
    const float* __restrict__ qw, const float* __restrict__ kw,
    const float* __restrict__ vw, const float* __restrict__ pw,
    const float* __restrict__ th1w, const float* __restrict__ th1b,
    const float* __restrict__ bias_seg, const float* __restrict__ vlw,
    const float* __restrict__ x,
    u16* __restrict__ wqkv, u16* __restrict__ pwb, float* __restrict__ biasmix,
    u16* __restrict__ wpack, u16* __restrict__ xb)
{
    __shared__ float t[32][33];
    const int bid = blockIdx.x;
    if (bid < 960) {
        const int i = (bid * 256 + threadIdx.x) * 4;
        const float* src; u16* dst;
        if (i < 98304)       { src = qw + i;            dst = wqkv + i; }
        else if (i < 196608) { src = kw + (i - 98304);  dst = wqkv + i; }
        else if (i < 589824) { src = vw + (i - 196608); dst = wqkv + i; }
        else                 { src = pw + (i - 589824); dst = pwb + (i - 589824); }
        float4 v = *(const float4*)src;
        u16x4 o;
        o[0] = f2b(v.x); o[1] = f2b(v.y); o[2] = f2b(v.z); o[3] = f2b(v.w);
        *(u16x4*)dst = o;
    } else if (bid == 960) {
        for (int i2 = threadIdx.x; i2 < 8 * NSP; i2 += 256) {
            int hh = i2 / NSP, off = i2 - hh * NSP;
            float a = th1b[hh];
            #pragma unroll
            for (int g = 0; g < 8; ++g) a += th1w[hh * 8 + g] * bias_seg[g * NSP + off];
            biasmix[i2] = a;
        }
    } else if (bid < 997) {
        int i2 = (bid - 961) * 256 + threadIdx.x;   // 0..9215
        if (i2 < 9216) {
            int g = i2 / 72, r = i2 - g * 72;       // wpack[g*72+tap*8+t]=vlw[(g*8+t)*9+tap]
            int tap = r >> 3, tt = r & 7;
            wpack[i2] = f2b(vlw[(g * 8 + tt) * 9 + tap]);
        }
    } else {
        const int L = bid - 997;             // 5376 blocks
        const int b = L / 84, r = L - b * 84;
        const int c0 = (r / 7) * 32, n0 = (r % 7) * 32;
        const int tx = threadIdx.x & 31, ty = threadIdx.x >> 5;
        #pragma unroll
        for (int l = 0; l < 4; ++l) {
            int c = c0 + ty + 8 * l, n = n0 + tx;
            t[ty + 8 * l][tx] = (n < NSP) ? x[((long)b * DIM + c) * NSP + n] : 0.f;
        }
        __syncthreads();
        #pragma unroll
        for (int l = 0; l < 4; ++l) {
            int n = n0 + ty + 8 * l, c = c0 + tx;
            if (n < NSP) xb[((long)b * NSP + n) * DIM + c] = f2b(t[tx][ty + 8 * l]);
        }
    }
}

// ---------------- K1: QKV projection (MFMA, BK=64), XCD-aware grid --------
// grid 1248 (1-D): xcd=bid&7, q=bid>>3, oc_t=q%12, m_t=xcd+8*(q/12).
// Epilogue: C staged in LDS (bank-swizzled), then coalesced 16B stores.
__global__ __launch_bounds__(256) void k_qkv(
    const u16* __restrict__ xb, const u16* __restrict__ wqkv,
    const float* __restrict__ qb, const float* __restrict__ kb,
    const float* __restrict__ vb,
    u16* __restrict__ qt, u16* __restrict__ kb16, u16* __restrict__ vt)
{
    const int g = blockIdx.x;
    const int xcd = g & 7, q = g >> 3;
    const int oc_t = q % 12, mg = q / 12;
    const int m_t = xcd + 8 * mg;
    if (m_t >= 98) return;
    __shared__ u16 LDS[16384];          // A(8192) + B(8192); reused as 128x128 C
    const int m0 = m_t * 128, oc0 = oc_t * 128;
    f32x4 acc[4][4];
    gemm128_bk64((const char*)xb + (long)m0 * 768, 768,
                 (const char*)wqkv + (long)oc0 * 768, 768, 6,
                 LDS, LDS + 8192, acc);

    const int tid = threadIdx.x, wid = tid >> 6, lane = tid & 63;
    const int wm = (wid & 1) * 64, wn = (wid >> 1) * 64;
    const int col = lane & 15, quad = lane >> 4;

    // per-thread bias for the 4 j-columns (oc = oc0 + wn + j*16 + col)
    float bias[4];
    {
        const int ocb = oc0 + wn + col;
        if (oc0 < 256) {
            #pragma unroll
            for (int j = 0; j < 4; ++j) bias[j] = qb[ocb + j * 16];
        } else if (oc0 < 512) {
            #pragma unroll
            for (int j = 0; j < 4; ++j) bias[j] = kb[ocb - 256 + j * 16];
        } else {
            #pragma unroll
            for (int j = 0; j < 4; ++j) bias[j] = vb[ocb - 512 + j * 16];
        }
    }

    // stage C (bf16, +bias) into LDS; swizzle 32B col-group by (lm>>2)&3
    // -> per store inst the 4 quads hit 4 disjoint bank octets (no conflict)
    #pragma unroll
    for (int i = 0; i < 4; ++i) {
        #pragma unroll
        for (int r = 0; r < 4; ++r) {
            const int lm = wm + i * 16 + quad * 4 + r;
            const int kx = ((lm >> 2) & 3) << 4;
            #pragma unroll
            for (int j = 0; j < 4; ++j) {
                const int lc = wn + j * 16 + col;
                LDS[lm * 128 + (lc ^ kx)] = f2b(acc[i][j][r] + bias[j]);
            }
        }
    }
    __syncthreads();

    // coalesced store: 2048 16B chunks; lanes 0-15 = one 256B row segment
    #pragma unroll
    for (int t = 0; t < 8; ++t) {
        const int ch = tid + t * 256;
        const int lm = ch >> 4, seg = ch & 15;
        const int k2 = (lm >> 2) & 3;
        bf16x8 v = *(const bf16x8*)&LDS[lm * 128 + ((seg ^ (k2 << 1)) << 3)];
        const int m = m0 + lm;
        u16* dst;
        if (oc0 < 256) {
            dst = &qt[(long)m * 256 + oc0 + seg * 8];
        } else if (oc0 < 512) {
            dst = &kb16[(long)m * 256 + (oc0 - 256) + seg * 8];
        } else {
            const int b = m / NSP, n = m - b * NSP;
            dst = &vt[(((long)b * NHD + ((oc0 - 512) >> 7)) * NSP + n) * DVV + seg * 8];
        }
        *(bf16x8*)dst = v;
    }
}

// ---------------- K2: per-plane vtT transpose + dwconv from LDS ----------
// 512 blocks, one per (b,h) plane. Stage 196x128 bf16 plane in LDS
// ([196][PROW=136] u16 = 53,312 B), then:
//  (a) transpose-write vtT rows, n-paired halves (32 lines/inst, optimal)
//  (b) 3x3 depthwise conv with all taps read from LDS -> vlt (n-major)
__global__ __launch_bounds__(256) void k_vtdw(
    const u16* __restrict__ vt, const u16* __restrict__ wpack,
    const float* __restrict__ vlb,
    u16* __restrict__ vtT, u16* __restrict__ vlt)
{
    __shared__ u16 P[NSP * PROW];
    const int bh = blockIdx.x;
    const int tid = threadIdx.x;
    const int h = bh & 7;
    const long plane = (long)bh * NSP * DVV;

    // stage: 13 iters x 16 n-rows; thread (nrow=tid>>4, dseg=tid&15)
    {
        const int dseg = tid & 15, nrow = tid >> 4;
        #pragma unroll
        for (int i = 0; i < 13; ++i) {
            int n = i * 16 + nrow;
            if (n < NSP)
                *(bf16x8*)&P[n * PROW + dseg * 8] =
                    *(const bf16x8*)&vt[plane + (long)n * DVV + dseg * 8];
        }
    }
    __syncthreads();

    // (a) transpose out: thread (d=tid>>1, hh=tid&1); per 32-n block the
    // two halves (hh*16) are line-adjacent -> 32 transactions per inst.
    {
        const int d = tid >> 1, hh = tid & 1;
        const long orow = ((long)bh * DVV + d) * 224;
        #pragma unroll
        for (int nb = 0; nb < 7; ++nb) {
            const int n0s = nb * 32 + hh * 16;
            u16 tmp[16];
            #pragma unroll
            for (int j = 0; j < 16; ++j) {
                int n = n0s + j;
                tmp[j] = (n < NSP) ? P[n * PROW + d] : (u16)0;
            }
            *(bf16x8*)&vtT[orow + n0s]     = *(const bf16x8*)&tmp[0];
            *(bf16x8*)&vtT[orow + n0s + 8] = *(const bf16x8*)&tmp[8];
        }
    }

    // (b) dwconv from LDS (no barrier needed: P is read-only now)
    {
        const int dg = tid & 15, nl = tid >> 4;
        const int d0 = dg * 8;
        const u16* wb = wpack + (h * 16 + dg) * 72;
        bf16x8 wv[9];
        #pragma unroll
        for (int tap = 0; tap < 9; ++tap) wv[tap] = *(const bf16x8*)&wb[tap * 8];
        float bias[8];
        #pragma unroll
        for (int k2 = 0; k2 < 8; ++k2) bias[k2] = vlb[h * DVV + d0 + k2];
        #pragma unroll
        for (int c = 0; c < 13; ++c) {
            const int n = c * 16 + nl;
            if (n >= NSP) break;
            const int y = n / RES, xx = n - y * RES;
            float acc[8];
            #pragma unroll
            for (int k2 = 0; k2 < 8; ++k2) acc[k2] = bias[k2];
            #pragma unroll
            for (int dy = -1; dy <= 1; ++dy) {
                int yy = y + dy;
                if (yy < 0 || yy >= RES) continue;
                #pragma unroll
                for (int dx = -1; dx <= 1; ++dx) {
                    int xn = xx + dx;
                    if (xn < 0 || xn >= RES) continue;
                    int tap = (dy + 1) * 3 + dx + 1;
                    bf16x8 v = *(const bf16x8*)&P[(yy * RES + xn) * PROW + d0];
                    #pragma unroll
                    for (int k2 = 0; k2 < 8; ++k2)
                        acc[k2] += b2f((u16)wv[tap][k2]) * b2f((u16)v[k2]);
                }
            }
            bf16x8 r;
            #pragma unroll
            for (int k2 = 0; k2 < 8; ++k2) r[k2] = (short)f2b(acc[k2]);
            *(bf16x8*)&vlt[plane + (long)n * DVV + d0] = r;
        }
    }
}

// ---------------- K3: fused attention middle (phases 1-4 EXACT r14..r23) --
// grid 832: xcd = L&7, b = xcd + 8*(wq/13), strip = wq%13, n0 = strip*16.
// S: 128 rows x 224 u16 = 57,344 B + bmS 3,136 B -> 2 blocks/CU (16 waves).
// Phase 5 epilogue: O-tile staged in dead S (quad-XOR swizzle), then 4
// coalesced 16B stores/thread (64 lanes = 1KB/inst).
__global__ __launch_bounds__(512, 2) void k_attn2(
    const u16* __restrict__ qt, const u16* __restrict__ kb16,
    const u16* __restrict__ vtT, const u16* __restrict__ vlt,
    const float* __restrict__ th1w, const float* __restrict__ th2w,
    const float* __restrict__ th2b, const float* __restrict__ biasmix,
    u16* __restrict__ ot)
{
    __shared__ u16 S[128 * SROW];
    __shared__ u16 bmS[8 * NSP];
    const int tid = threadIdx.x;
    const int L  = blockIdx.x;
    const int wq = L >> 3;
    const int b  = (L & 7) + ((wq / NSTRIP) << 3);
    const int n0 = (wq % NSTRIP) * 16;
    const int wid = tid >> 6, lane = tid & 63;
    const int l15 = lane & 15, lq8 = (lane >> 4) * 8;
    const int quad = lane >> 4, col = lane & 15;

    for (int i = tid; i < 8 * NSP; i += 512) bmS[i] = f2b(biasmix[i]);
    __syncthreads();

    // ---- phase 1: scores (MFMA) + th1 mix + bias, fused in registers ----
    {
        const long qrow = ((long)(b * NSP) + n0 + l15) * NQK;
        bf16x8 af[8];
        #pragma unroll
        for (int g = 0; g < 8; ++g)
            af[g] = *(const bf16x8*)&qt[qrow + g * 32 + lq8];
        #pragma unroll
        for (int jj = 0; jj < 2; ++jj) {
            const int j = wid + jj * 8;
            if (j >= 13) break;              // j=13 strip is garbage (phase 4 zeroes)
            const long krow = ((long)(b * NSP) + j * 16 + l15) * NQK;
            f32x4 t[8];
            #pragma unroll
            for (int g = 0; g < 8; ++g) {
                bf16x8 bv = *(const bf16x8*)&kb16[krow + g * 32 + lq8];
                t[g] = __builtin_amdgcn_mfma_f32_16x16x32_bf16(
                    af[g], bv, (f32x4){0.f, 0.f, 0.f, 0.f}, 0, 0, 0);
            }
            const int m = j * 16 + col;
            const int ym = m / RES, xm = m - ym * RES;
            int offr[4];
            #pragma unroll
            for (int r = 0; r < 4; ++r) {
                int gn = n0 + quad * 4 + r;
                int yn = gn / RES, xn = gn - yn * RES;
                int off = abs(yn - ym) * RES + abs(xn - xm);
                offr[r] = (off > 195) ? 195 : off;   // garbage rows/cols only
            }
            #pragma unroll
            for (int h = 0; h < 8; ++h) {
                float o[4];
                #pragma unroll
                for (int r = 0; r < 4; ++r) o[r] = b2f(bmS[h * NSP + offr[r]]);
                #pragma unroll
                for (int g = 0; g < 8; ++g) {
                    const float w = th1w[h * 8 + g] * SCALE;  // SGPR
                    #pragma unroll
                    for (int r = 0; r < 4; ++r) o[r] += w * t[g][r];
                }
                #pragma unroll
                for (int r = 0; r < 4; ++r)
                    S[(h * 16 + quad * 4 + r) * SROW + m] = f2b(o[r]);
            }
        }
    }
    __syncthreads();

    // ---- phase 3: softmax, 4 rows per wave concurrently (16-lane groups) ----
    {
        const int c = lane & 15, rg = lane >> 4;
        #pragma unroll
        for (int it = 0; it < 4; ++it) {
            u16* row = &S[(wid * 16 + it * 4 + rg) * SROW];
            float v[13];
            #pragma unroll
            for (int k = 0; k < 12; ++k) v[k] = b2f(row[c + 16 * k]);
            v[12] = (c < 4) ? b2f(row[192 + c]) : -1e30f;
            float mx = v[0];
            #pragma unroll
            for (int k = 1; k < 13; ++k) mx = fmaxf(mx, v[k]);
            #pragma unroll
            for (int o = 1; o < 16; o <<= 1) mx = fmaxf(mx, __shfl_xor(mx, o));
            float sum = 0.f;
            #pragma unroll
            for (int k = 0; k < 13; ++k) { v[k] = __expf(v[k] - mx); sum += v[k]; }
            if (c >= 4) sum -= v[12];   // garbage lane contribution
            #pragma unroll
            for (int o = 1; o < 16; o <<= 1) sum += __shfl_xor(sum, o);
            float inv = 1.0f / sum;
            #pragma unroll
            for (int k = 0; k < 12; ++k) row[c + 16 * k] = f2b(v[k] * inv);
            if (c < 4) row[192 + c] = f2b(v[12] * inv);
        }
    }
    __syncthreads();

    // ---- phase 4: th2 mix (+bias), zero pad m in [196,224), paired u32 ----
    {
        for (int p = tid; p < 16 * 112; p += 512) {
            const int nl = p / 112, kp = p - nl * 112;
            const int m0 = kp * 2;
            if (m0 >= NSP) {
                #pragma unroll
                for (int h = 0; h < 8; ++h)
                    *(u32*)&S[(h * 16 + nl) * SROW + m0] = 0u;
                continue;
            }
            float s0[8], s1[8];
            #pragma unroll
            for (int g = 0; g < 8; ++g) {
                u32 v = *(const u32*)&S[(g * 16 + nl) * SROW + m0];
                s0[g] = b2f((u16)(v & 0xffff));
                s1[g] = b2f((u16)(v >> 16));
            }
            #pragma unroll
            for (int h = 0; h < 8; ++h) {
                float o0 = th2b[h], o1 = th2b[h];
                #pragma unroll
                for (int g = 0; g < 8; ++g) {
                    const float w = th2w[h * 8 + g];   // SGPR
                    o0 += w * s0[g];
                    o1 += w * s1[g];
                }
                *(u32*)&S[(h * 16 + nl) * SROW + m0] =
                    (u32)f2b(o0) | ((u32)f2b(o1) << 16);
            }
        }
    }
    __syncthreads();

    // ---- phase 5: O = P @ V + vlocal, ReLU; O-tile staged in dead S ------
    {
        const int h = wid;
        const long vrow = (long)(b * NHD + h) * DVV;
        f32x4 acc[8];
        #pragma unroll
        for (int df = 0; df < 8; ++df) acc[df] = (f32x4){0.f, 0.f, 0.f, 0.f};
        for (int kc = 0; kc < 7; ++kc) {
            bf16x8 a0 = *(const bf16x8*)&S[(h * 16 + l15) * SROW + kc * 32 + lq8];
            #pragma unroll
            for (int df = 0; df < 8; ++df) {
                bf16x8 bv = *(const bf16x8*)&vtT[(vrow + df * 16 + l15) * 224 + kc * 32 + lq8];
                acc[df] = __builtin_amdgcn_mfma_f32_16x16x32_bf16(a0, bv, acc[df], 0, 0, 0);
            }
        }
        __syncthreads();   // all waves done reading P from S

        // stage O (bf16, +vlocal, ReLU) as S[16 rows][1024], quad-XOR swizzle
        const long lbase = (long)(b * NHD + h) * NSP;
        #pragma unroll
        for (int df = 0; df < 8; ++df) {
            const int d = df * 16 + col;
            #pragma unroll
            for (int r = 0; r < 4; ++r) {
                const int lm = quad * 4 + r;
                const int n = n0 + lm;
                const int nn = (n < NSP) ? n : (NSP - 1);  // clamp: unused if n>=NSP
                float v = acc[df][r] + b2f(vlt[(lbase + nn) * DVV + d]);
                const int kx = ((lm >> 2) & 3) << 4;
                S[lm * 1024 + ((h * 128 + d) ^ kx)] = f2b(fmaxf(v, 0.f));
            }
        }
    }
    __syncthreads();

    // coalesced ot store: 16 rows x 2048B; 4 chunks of 16B per thread,
    // 64 consecutive lanes = 1KB contiguous per instruction.
    {
        #pragma unroll
        for (int t = 0; t < 4; ++t) {
            const int ch = tid + t * 512;        // 0..2047
            const int lm = ch >> 7, seg = ch & 127;
            const int k2 = (lm >> 2) & 3;
            bf16x8 v = *(const bf16x8*)&S[lm * 1024 + ((seg ^ (k2 << 1)) << 3)];
            const int n = n0 + lm;
            if (n < NSP)
                *(bf16x8*)&ot[((long)(b * NSP + n)) * 1024 + seg * 8] = v;
        }
    }
}

// ---------------- K5: output projection (MFMA, BK=64), XCD-aware grid -----
// grid 600 (1-D): xcd=bid&7, q=bid>>3, o_t=q%3, m_t=xcd+8*(q/3).
// Epilogue: C (128oc x 64m f32) staged in the dead A+B LDS (32KB exactly),
// m-block XOR swizzle by quad=(oc>>2)&3; then coalesced f32 stores (each
// wave sweeps 64 consecutive m -> one 256B transaction).
__global__ __launch_bounds__(256) void k_proj(
    const u16* __restrict__ pwb, const u16* __restrict__ ot,
    const float* __restrict__ projb, float* __restrict__ outp)
{
    const int g = blockIdx.x;
    const int xcd = g & 7, q = g >> 3;
    const int o_t = q % 3, mgq = q / 3;
    const int m_t = xcd + 8 * mgq;
    if (m_t >= 196) return;
    __shared__ u16 LDS[16384];    // A(8192 u16) + B(4096 u16); reused: f32 C[128][64]
    u16* A_lds = LDS;
    u16* B_lds = LDS + 8192;
    const int tid = threadIdx.x, wid = tid >> 6, lane = tid & 63;
    const int lrow = lane >> 2, lcb = (lane & 3) << 4;
    const int m0 = m_t * 64, oc0 = o_t * 128;
    const int wm = (wid & 1) * 64, wn = (wid >> 1) * 32;
    const int l15 = lane & 15, lq8 = (lane >> 4) * 8;

    const char* gp[6];
    u16* lp[6];
    #pragma unroll
    for (int t = 0; t < 6; ++t) {
        int s = wid * 6 + t;            // 0..23
        int sub = s / 12, s12 = s - sub * 12;
        if (s12 < 8) {
            gp[t] = (const char*)pwb + (long)(oc0 + s12 * 16 + lrow) * 2048 + lcb + sub * 64;
            lp[t] = A_lds + sub * 4096 + s12 * 512;
        } else {
            gp[t] = (const char*)ot + (long)(m0 + (s12 - 8) * 16 + lrow) * 2048 + lcb + sub * 64;
            lp[t] = B_lds + sub * 2048 + (s12 - 8) * 512;
        }
    }

    f32x4 acc[4][2];
    #pragma unroll
    for (int i = 0; i < 4; ++i)
        #pragma unroll
        for (int j = 0; j < 2; ++j) acc[i][j] = (f32x4){0.f, 0.f, 0.f, 0.f};

    for (int kk = 0; kk < 16; ++kk) {
        #pragma unroll
        for (int t = 0; t < 6; ++t) { gld16(gp[t], lp[t]); gp[t] += 128; }
        __syncthreads();
        #pragma unroll
        for (int s = 0; s < 2; ++s) {
            bf16x8 af[4], bfr[2];
            #pragma unroll
            for (int i = 0; i < 4; ++i)
                af[i] = *(const bf16x8*)&A_lds[s * 4096 + (wm + i * 16 + l15) * 32 + lq8];
            #pragma unroll
            for (int j = 0; j < 2; ++j)
                bfr[j] = *(const bf16x8*)&B_lds[s * 2048 + (wn + j * 16 + l15) * 32 + lq8];
            #pragma unroll
            for (int i = 0; i < 4; ++i)
                #pragma unroll
                for (int j = 0; j < 2; ++j)
                    acc[i][j] = __builtin_amdgcn_mfma_f32_16x16x32_bf16(
                        af[i], bfr[j], acc[i][j], 0, 0, 0);
        }
        __syncthreads();
    }

    // stage C into LDS as f32[128][64], m-block swizzled by quad
    float* C = (float*)LDS;
    const int col = lane & 15, quad = lane >> 4;
    #pragma unroll
    for (int i = 0; i < 4; ++i) {
        #pragma unroll
        for (int j = 0; j < 2; ++j) {
            #pragma unroll
            for (int r = 0; r < 4; ++r) {
                const int oc_l = wm + i * 16 + quad * 4 + r;
                const int m_l  = wn + j * 16 + col;
                C[oc_l * 64 + (m_l ^ (quad << 4))] = acc[i][j][r];
            }
        }
    }
    __syncthreads();

    // coalesced store: wave sweeps 64 consecutive m of one oc row
    #pragma unroll
    for (int t = 0; t < 32; ++t) {
        const int e = tid + t * 256;
        const int oc_l = e >> 6, m_l = e & 63;
        const int swz = ((oc_l >> 2) & 3) << 4;
        float v = C[oc_l * 64 + (m_l ^ swz)] + projb[oc0 + oc_l];
        const int m_g = m0 + m_l;
        const int b = m_g / NSP, n = m_g - b * NSP;
        outp[((long)b * DIM + oc0 + oc_l) * NSP + n] = v;
    }
}

extern "C" void kernel_launch(void* const* d_in, const int* in_sizes, int n_in,
                              void* d_out, int out_size, void* d_ws, size_t ws_size,
                              hipStream_t stream) {
    const float* x        = (const float*)d_in[0];
    const float* qw       = (const float*)d_in[1];
    const float* qb       = (const float*)d_in[2];
    const float* kw       = (const float*)d_in[3];
    const float* kb       = (const float*)d_in[4];
    const float* vw       = (const float*)d_in[5];
    const float* vb       = (const float*)d_in[6];
    const float* vlw      = (const float*)d_in[7];
    const float* vlb      = (const float*)d_in[8];
    const float* th1w     = (const float*)d_in[9];
    const float* th1b     = (const float*)d_in[10];
    const float* th2w     = (const float*)d_in[11];
    const float* th2b     = (const float*)d_in[12];
    const float* projw    = (const float*)d_in[13];
    const float* projb    = (const float*)d_in[14];
    const float* bias_seg = (const float*)d_in[15];
    float* outp = (float*)d_out;

    // workspace layout (bytes, 16B aligned) -- identical to r14..r23
    char* w = (char*)d_ws;
    u16* xb      = (u16*)(w);                 //  9,633,792
    u16* wqkv    = (u16*)(w + 9633792);       //  1,179,648
    u16* pwb     = (u16*)(w + 10813440);      //    786,432
    u16* wpack   = (u16*)(w + 11599872);      //     18,432
    float* bmix  = (float*)(w + 11618304);    //      6,400
    u16* qt      = (u16*)(w + 11624704);      //  6,455,296 (12608 rows x 256)
    u16* kb16    = (u16*)(w + 18080000);      //  6,455,296
    u16* vt      = (u16*)(w + 24535296);      // 25,690,112
    u16* vtT     = (u16*)(w + 50225408);      // 29,360,128 (rows padded 224)
    u16* ot      = (u16*)(w + 79585536);      // 25,690,112
    u16* vlt     = (u16*)(w + 105275648);     // 25,690,112
    // total 130,965,760 B

    k_prep<<<dim3(6373), 256, 0, stream>>>(qw, kw, vw, projw, th1w, th1b,
                                           bias_seg, vlw, x, wqkv, pwb, bmix,
                                           wpack, xb);
    k_qkv<<<dim3(1248), 256, 0, stream>>>(xb, wqkv, qb, kb, vb, qt, kb16, vt);
    k_vtdw<<<dim3(512), 256, 0, stream>>>(vt, wpack, vlb, vtT, vlt);
    k_attn2<<<dim3(NSTRIP * 64), 512, 0, stream>>>(qt, kb16, vtT, vlt, th1w, th2w,
                                                   th2b, bmix, ot);
    k_proj<<<dim3(600), 256, 0, stream>>>(pwb, ot, projb, outp);
}

// Round 15
// 247.529 us; speedup vs baseline: 1.0696x; 1.0696x over previous
//
#include <hip/hip_runtime.h>
#include <hip/hip_bf16.h>

// Attention4D MI355X round 26 (r25 + s_setprio around attn2 MFMA clusters):
//  - r25 confirmed: ot WRITE line-perfect (exactly 25088KB, was 26.9-29.6MB).
//    All global store paths now coalesced. attn2 remains latency-bound
//    (all pipes <30%), restructures 0/5 -- only scheduler-level levers left.
//  - T5: __builtin_amdgcn_s_setprio(1)/(0) around phase-1 and phase-5 MFMA
//    clusters. Preconditions match the catalog's measured +4-7% attn case:
//    2 independent blocks/CU + intra-block wave phase diversity (waves 5-7
//    do 1 j in phase 1, waves 0-4 do 2). Zero semantic risk.
//  - Everything else byte-identical to r25 (264.8us slow-session).
// B=64, DIM=384, N=196 (14x14), NH=8, KD=32, DV=128.

#define RES   14
#define NSP   196
#define NHD   8
#define KDIM  32
#define DVV   128
#define DIM   384
#define NQK   256
#define SCALE 0.17677669529663687f
#define SROW  224    // LDS score row stride (u16); 448B ≡ bank16: 2-way, free
#define PROW  136    // k_vtdw plane row stride (u16); 272B: 16B-aligned, +4 banks
#define NSTRIP 13    // 13 x 16 = 208 >= 196

typedef __attribute__((ext_vector_type(8))) short bf16x8;
typedef __attribute__((ext_vector_type(4))) float f32x4;
typedef __attribute__((ext_vector_type(4))) unsigned short u16x4;
typedef unsigned short u16;
typedef unsigned int u32;

__device__ __forceinline__ u16 f2b(float f) {
    union { __hip_bfloat16 b; u16 u; } c; c.b = __float2bfloat16(f); return c.u;
}
__device__ __forceinline__ float b2f(u16 u) {
    union { __hip_bfloat16 b; u16 u; } c; c.u = u; return __bfloat162float(c.b);
}

// async global->LDS, 16B per lane; LDS dest = wave-uniform base + lane*16
__device__ __forceinline__ void gld16(const void* g, void* l) {
    __builtin_amdgcn_global_load_lds(
        (__attribute__((address_space(1))) void*)(unsigned long long)(const char*)g,
        (__attribute__((address_space(3))) void*)l, 16, 0, 0);
}

// ---- 128x128 bf16 MFMA GEMM core, BK=64 (two BK=32 sub-tiles / barrier) ----
__device__ __forceinline__ void gemm128_bk64(const char* Aseg, long rbA,
                                             const char* Bseg, long rbB, int kIters,
                                             u16* A_lds, u16* B_lds, f32x4 acc[4][4])
{
    const int tid  = threadIdx.x;
    const int wid  = tid >> 6;
    const int lane = tid & 63;
    const int lrow = lane >> 2;
    const int lcb  = (lane & 3) << 4;
    const int r0   = wid * 32;
    const int wm   = (wid & 1) * 64, wn = (wid >> 1) * 64;
    const int l15  = lane & 15, lq8 = (lane >> 4) * 8;

    #pragma unroll
    for (int i = 0; i < 4; ++i)
        #pragma unroll
        for (int j = 0; j < 4; ++j) acc[i][j] = (f32x4){0.f, 0.f, 0.f, 0.f};

    const char* ap0 = Aseg + (long)(r0 + lrow) * rbA + lcb;
    const char* ap1 = ap0 + 16 * rbA;
    const char* bp0 = Bseg + (long)(r0 + lrow) * rbB + lcb;
    const char* bp1 = bp0 + 16 * rbB;
    u16* la0 = A_lds + r0 * 32;
    u16* la1 = la0 + 512;
    u16* lb0 = B_lds + r0 * 32;
    u16* lb1 = lb0 + 512;

    for (int kk = 0; kk < kIters; ++kk) {
        gld16(ap0, la0);        gld16(ap1, la1);
        gld16(bp0, lb0);        gld16(bp1, lb1);
        gld16(ap0 + 64, la0 + 4096); gld16(ap1 + 64, la1 + 4096);
        gld16(bp0 + 64, lb0 + 4096); gld16(bp1 + 64, lb1 + 4096);
        ap0 += 128; ap1 += 128; bp0 += 128; bp1 += 128;
        __syncthreads();
        #pragma unroll
        for (int s = 0; s < 2; ++s) {
            bf16x8 af[4], bfr[4];
            #pragma unroll
            for (int i = 0; i < 4; ++i)
                af[i] = *(const bf16x8*)&A_lds[s * 4096 + (wm + i * 16 + l15) * 32 + lq8];
            #pragma unroll
            for (int j = 0; j < 4; ++j)
                bfr[j] = *(const bf16x8*)&B_lds[s * 4096 + (wn + j * 16 + l15) * 32 + lq8];
            #pragma unroll
            for (int i = 0; i < 4; ++i)
                #pragma unroll
                for (int j = 0; j < 4; ++j)
                    acc[i][j] = __builtin_amdgcn_mfma_f32_16x16x32_bf16(
                        af[i], bfr[j], acc[i][j], 0, 0, 0);
        }
        __syncthreads();
    }
}

// ---------------- prep (merged): weights + biasmix + wpack + x transpose ----
// blocks [0,960): float4-vectorized weight conversions (4 elems/thread);
// 960: biasmix; [961,997): wpack; [997,6373): x transpose.
__global__ __launch_bounds__(256) void k_prep(
    const float* __restrict__ qw, const float* __restrict__ kw,
    const float* __restrict__ vw, const float* __restrict__ pw,
    const float* __restrict__ th1w, const float* __restrict__ th1b,
    const float* __restrict__ bias_seg, const float* __restrict__ vlw,
    const float* __restrict__ x,
    u16* __restrict__ wqkv, u16* __restrict__ pwb, float* __restrict__ biasmix,
    u16* __restrict__ wpack, u16* __restrict__ xb)
{
    __shared__ float t[32][33];
    const int bid = blockIdx.x;
    if (bid < 960) {
        const int i = (bid * 256 + threadIdx.x) * 4;
        const float* src; u16* dst;
        if (i < 98304)       { src = qw + i;            dst = wqkv + i; }
        else if (i < 196608) { src = kw + (i - 98304);  dst = wqkv + i; }
        else if (i < 589824) { src = vw + (i - 196608); dst = wqkv + i; }
        else                 { src = pw + (i - 589824); dst = pwb + (i - 589824); }
        float4 v = *(const float4*)src;
        u16x4 o;
        o[0] = f2b(v.x); o[1] = f2b(v.y); o[2] = f2b(v.z); o[3] = f2b(v.w);
        *(u16x4*)dst = o;
    } else if (bid == 960) {
        for (int i2 = threadIdx.x; i2 < 8 * NSP; i2 += 256) {
            int hh = i2 / NSP, off = i2 - hh * NSP;
            float a = th1b[hh];
            #pragma unroll
            for (int g = 0; g < 8; ++g) a += th1w[hh * 8 + g] * bias_seg[g * NSP + off];
            biasmix[i2] = a;
        }
    } else if (bid < 997) {
        int i2 = (bid - 961) * 256 + threadIdx.x;   // 0..9215
        if (i2 < 9216) {
            int g = i2 / 72, r = i2 - g * 72;       // wpack[g*72+tap*8+t]=vlw[(g*8+t)*9+tap]
            int tap = r >> 3, tt = r & 7;
            wpack[i2] = f2b(vlw[(g * 8 + tt) * 9 + tap]);
        }
    } else {
        const int L = bid - 997;             // 5376 blocks
        const int b = L / 84, r = L - b * 84;
        const int c0 = (r / 7) * 32, n0 = (r % 7) * 32;
        const int tx = threadIdx.x & 31, ty = threadIdx.x >> 5;
        #pragma unroll
        for (int l = 0; l < 4; ++l) {
            int c = c0 + ty + 8 * l, n = n0 + tx;
            t[ty + 8 * l][tx] = (n < NSP) ? x[((long)b * DIM + c) * NSP + n] : 0.f;
        }
        __syncthreads();
        #pragma unroll
        for (int l = 0; l < 4; ++l) {
            int n = n0 + ty + 8 * l, c = c0 + tx;
            if (n < NSP) xb[((long)b * NSP + n) * DIM + c] = f2b(t[tx][ty + 8 * l]);
        }
    }
}

// ---------------- K1: QKV projection (MFMA, BK=64), XCD-aware grid --------
// grid 1248 (1-D): xcd=bid&7, q=bid>>3, oc_t=q%12, m_t=xcd+8*(q/12).
// Epilogue: C staged in LDS (bank-swizzled), then coalesced 16B stores.
__global__ __launch_bounds__(256) void k_qkv(
    const u16* __restrict__ xb, const u16* __restrict__ wqkv,
    const float* __restrict__ qb, const float* __restrict__ kb,
    const float* __restrict__ vb,
    u16* __restrict__ qt, u16* __restrict__ kb16, u16* __restrict__ vt)
{
    const int g = blockIdx.x;
    const int xcd = g & 7, q = g >> 3;
    const int oc_t = q % 12, mg = q / 12;
    const int m_t = xcd + 8 * mg;
    if (m_t >= 98) return;
    __shared__ u16 LDS[16384];          // A(8192) + B(8192); reused as 128x128 C
    const int m0 = m_t * 128, oc0 = oc_t * 128;
    f32x4 acc[4][4];
    gemm128_bk64((const char*)xb + (long)m0 * 768, 768,
                 (const char*)wqkv + (long)oc0 * 768, 768, 6,
                 LDS, LDS + 8192, acc);

    const int tid = threadIdx.x, wid = tid >> 6, lane = tid & 63;
    const int wm = (wid & 1) * 64, wn = (wid >> 1) * 64;
    const int col = lane & 15, quad = lane >> 4;

    // per-thread bias for the 4 j-columns (oc = oc0 + wn + j*16 + col)
    float bias[4];
    {
        const int ocb = oc0 + wn + col;
        if (oc0 < 256) {
            #pragma unroll
            for (int j = 0; j < 4; ++j) bias[j] = qb[ocb + j * 16];
        } else if (oc0 < 512) {
            #pragma unroll
            for (int j = 0; j < 4; ++j) bias[j] = kb[ocb - 256 + j * 16];
        } else {
            #pragma unroll
            for (int j = 0; j < 4; ++j) bias[j] = vb[ocb - 512 + j * 16];
        }
    }

    // stage C (bf16, +bias) into LDS; swizzle 32B col-group by (lm>>2)&3
    // -> per store inst the 4 quads hit 4 disjoint bank octets (no conflict)
    #pragma unroll
    for (int i = 0; i < 4; ++i) {
        #pragma unroll
        for (int r = 0; r < 4; ++r) {
            const int lm = wm + i * 16 + quad * 4 + r;
            const int kx = ((lm >> 2) & 3) << 4;
            #pragma unroll
            for (int j = 0; j < 4; ++j) {
                const int lc = wn + j * 16 + col;
                LDS[lm * 128 + (lc ^ kx)] = f2b(acc[i][j][r] + bias[j]);
            }
        }
    }
    __syncthreads();

    // coalesced store: 2048 16B chunks; lanes 0-15 = one 256B row segment
    #pragma unroll
    for (int t = 0; t < 8; ++t) {
        const int ch = tid + t * 256;
        const int lm = ch >> 4, seg = ch & 15;
        const int k2 = (lm >> 2) & 3;
        bf16x8 v = *(const bf16x8*)&LDS[lm * 128 + ((seg ^ (k2 << 1)) << 3)];
        const int m = m0 + lm;
        u16* dst;
        if (oc0 < 256) {
            dst = &qt[(long)m * 256 + oc0 + seg * 8];
        } else if (oc0 < 512) {
            dst = &kb16[(long)m * 256 + (oc0 - 256) + seg * 8];
        } else {
            const int b = m / NSP, n = m - b * NSP;
            dst = &vt[(((long)b * NHD + ((oc0 - 512) >> 7)) * NSP + n) * DVV + seg * 8];
        }
        *(bf16x8*)dst = v;
    }
}

// ---------------- K2: per-plane vtT transpose + dwconv from LDS ----------
// 512 blocks, one per (b,h) plane. Stage 196x128 bf16 plane in LDS
// ([196][PROW=136] u16 = 53,312 B), then:
//  (a) transpose-write vtT rows, n-paired halves (32 lines/inst, optimal)
//  (b) 3x3 depthwise conv with all taps read from LDS -> vlt (n-major)
__global__ __launch_bounds__(256) void k_vtdw(
    const u16* __restrict__ vt, const u16* __restrict__ wpack,
    const float* __restrict__ vlb,
    u16* __restrict__ vtT, u16* __restrict__ vlt)
{
    __shared__ u16 P[NSP * PROW];
    const int bh = blockIdx.x;
    const int tid = threadIdx.x;
    const int h = bh & 7;
    const long plane = (long)bh * NSP * DVV;

    // stage: 13 iters x 16 n-rows; thread (nrow=tid>>4, dseg=tid&15)
    {
        const int dseg = tid & 15, nrow = tid >> 4;
        #pragma unroll
        for (int i = 0; i < 13; ++i) {
            int n = i * 16 + nrow;
            if (n < NSP)
                *(bf16x8*)&P[n * PROW + dseg * 8] =
                    *(const bf16x8*)&vt[plane + (long)n * DVV + dseg * 8];
        }
    }
    __syncthreads();

    // (a) transpose out: thread (d=tid>>1, hh=tid&1); per 32-n block the
    // two halves (hh*16) are line-adjacent -> 32 transactions per inst.
    {
        const int d = tid >> 1, hh = tid & 1;
        const long orow = ((long)bh * DVV + d) * 224;
        #pragma unroll
        for (int nb = 0; nb < 7; ++nb) {
            const int n0s = nb * 32 + hh * 16;
            u16 tmp[16];
            #pragma unroll
            for (int j = 0; j < 16; ++j) {
                int n = n0s + j;
                tmp[j] = (n < NSP) ? P[n * PROW + d] : (u16)0;
            }
            *(bf16x8*)&vtT[orow + n0s]     = *(const bf16x8*)&tmp[0];
            *(bf16x8*)&vtT[orow + n0s + 8] = *(const bf16x8*)&tmp[8];
        }
    }

    // (b) dwconv from LDS (no barrier needed: P is read-only now)
    {
        const int dg = tid & 15, nl = tid >> 4;
        const int d0 = dg * 8;
        const u16* wb = wpack + (h * 16 + dg) * 72;
        bf16x8 wv[9];
        #pragma unroll
        for (int tap = 0; tap < 9; ++tap) wv[tap] = *(const bf16x8*)&wb[tap * 8];
        float bias[8];
        #pragma unroll
        for (int k2 = 0; k2 < 8; ++k2) bias[k2] = vlb[h * DVV + d0 + k2];
        #pragma unroll
        for (int c = 0; c < 13; ++c) {
            const int n = c * 16 + nl;
            if (n >= NSP) break;
            const int y = n / RES, xx = n - y * RES;
            float acc[8];
            #pragma unroll
            for (int k2 = 0; k2 < 8; ++k2) acc[k2] = bias[k2];
            #pragma unroll
            for (int dy = -1; dy <= 1; ++dy) {
                int yy = y + dy;
                if (yy < 0 || yy >= RES) continue;
                #pragma unroll
                for (int dx = -1; dx <= 1; ++dx) {
                    int xn = xx + dx;
                    if (xn < 0 || xn >= RES) continue;
                    int tap = (dy + 1) * 3 + dx + 1;
                    bf16x8 v = *(const bf16x8*)&P[(yy * RES + xn) * PROW + d0];
                    #pragma unroll
                    for (int k2 = 0; k2 < 8; ++k2)
                        acc[k2] += b2f((u16)wv[tap][k2]) * b2f((u16)v[k2]);
                }
            }
            bf16x8 r;
            #pragma unroll
            for (int k2 = 0; k2 < 8; ++k2) r[k2] = (short)f2b(acc[k2]);
            *(bf16x8*)&vlt[plane + (long)n * DVV + d0] = r;
        }
    }
}

// ---------------- K3: fused attention middle (phases 1-4 EXACT r14..r25) --
// grid 832: xcd = L&7, b = xcd + 8*(wq/13), strip = wq%13, n0 = strip*16.
// S: 128 rows x 224 u16 = 57,344 B + bmS 3,136 B -> 2 blocks/CU (16 waves).
// T5: s_setprio(1)/(0) around MFMA clusters (2 blocks/CU + wave imbalance
// give the scheduler something to arbitrate; catalog m191 +4-7% on attn).
__global__ __launch_bounds__(512, 2) void k_attn2(
    const u16* __restrict__ qt, const u16* __restrict__ kb16,
    const u16* __restrict__ vtT, const u16* __restrict__ vlt,
    const float* __restrict__ th1w, const float* __restrict__ th2w,
    const float* __restrict__ th2b, const float* __restrict__ biasmix,
    u16* __restrict__ ot)
{
    __shared__ u16 S[128 * SROW];
    __shared__ u16 bmS[8 * NSP];
    const int tid = threadIdx.x;
    const int L  = blockIdx.x;
    const int wq = L >> 3;
    const int b  = (L & 7) + ((wq / NSTRIP) << 3);
    const int n0 = (wq % NSTRIP) * 16;
    const int wid = tid >> 6, lane = tid & 63;
    const int l15 = lane & 15, lq8 = (lane >> 4) * 8;
    const int quad = lane >> 4, col = lane & 15;

    for (int i = tid; i < 8 * NSP; i += 512) bmS[i] = f2b(biasmix[i]);
    __syncthreads();

    // ---- phase 1: scores (MFMA) + th1 mix + bias, fused in registers ----
    {
        const long qrow = ((long)(b * NSP) + n0 + l15) * NQK;
        bf16x8 af[8];
        #pragma unroll
        for (int g = 0; g < 8; ++g)
            af[g] = *(const bf16x8*)&qt[qrow + g * 32 + lq8];
        #pragma unroll
        for (int jj = 0; jj < 2; ++jj) {
            const int j = wid + jj * 8;
            if (j >= 13) break;              // j=13 strip is garbage (phase 4 zeroes)
            const long krow = ((long)(b * NSP) + j * 16 + l15) * NQK;
            f32x4 t[8];
            __builtin_amdgcn_s_setprio(1);
            #pragma unroll
            for (int g = 0; g < 8; ++g) {
                bf16x8 bv = *(const bf16x8*)&kb16[krow + g * 32 + lq8];
                t[g] = __builtin_amdgcn_mfma_f32_16x16x32_bf16(
                    af[g], bv, (f32x4){0.f, 0.f, 0.f, 0.f}, 0, 0, 0);
            }
            __builtin_amdgcn_s_setprio(0);
            const int m = j * 16 + col;
            const int ym = m / RES, xm = m - ym * RES;
            int offr[4];
            #pragma unroll
            for (int r = 0; r < 4; ++r) {
                int gn = n0 + quad * 4 + r;
                int yn = gn / RES, xn = gn - yn * RES;
                int off = abs(yn - ym) * RES + abs(xn - xm);
                offr[r] = (off > 195) ? 195 : off;   // garbage rows/cols only
            }
            #pragma unroll
            for (int h = 0; h < 8; ++h) {
                float o[4];
                #pragma unroll
                for (int r = 0; r < 4; ++r) o[r] = b2f(bmS[h * NSP + offr[r]]);
                #pragma unroll
                for (int g = 0; g < 8; ++g) {
                    const float w = th1w[h * 8 + g] * SCALE;  // SGPR
                    #pragma unroll
                    for (int r = 0; r < 4; ++r) o[r] += w * t[g][r];
                }
                #pragma unroll
                for (int r = 0; r < 4; ++r)
                    S[(h * 16 + quad * 4 + r) * SROW + m] = f2b(o[r]);
            }
        }
    }
    __syncthreads();

    // ---- phase 3: softmax, 4 rows per wave concurrently (16-lane groups) ----
    {
        const int c = lane & 15, rg = lane >> 4;
        #pragma unroll
        for (int it = 0; it < 4; ++it) {
            u16* row = &S[(wid * 16 + it * 4 + rg) * SROW];
            float v[13];
            #pragma unroll
            for (int k = 0; k < 12; ++k) v[k] = b2f(row[c + 16 * k]);
            v[12] = (c < 4) ? b2f(row[192 + c]) : -1e30f;
            float mx = v[0];
            #pragma unroll
            for (int k = 1; k < 13; ++k) mx = fmaxf(mx, v[k]);
            #pragma unroll
            for (int o = 1; o < 16; o <<= 1) mx = fmaxf(mx, __shfl_xor(mx, o));
            float sum = 0.f;
            #pragma unroll
            for (int k = 0; k < 13; ++k) { v[k] = __expf(v[k] - mx); sum += v[k]; }
            if (c >= 4) sum -= v[12];   // garbage lane contribution
            #pragma unroll
            for (int o = 1; o < 16; o <<= 1) sum += __shfl_xor(sum, o);
            float inv = 1.0f / sum;
            #pragma unroll
            for (int k = 0; k < 12; ++k) row[c + 16 * k] = f2b(v[k] * inv);
            if (c < 4) row[192 + c] = f2b(v[12] * inv);
        }
    }
    __syncthreads();

    // ---- phase 4: th2 mix (+bias), zero pad m in [196,224), paired u32 ----
    {
        for (int p = tid; p < 16 * 112; p += 512) {
            const int nl = p / 112, kp = p - nl * 112;
            const int m0 = kp * 2;
            if (m0 >= NSP) {
                #pragma unroll
                for (int h = 0; h < 8; ++h)
                    *(u32*)&S[(h * 16 + nl) * SROW + m0] = 0u;
                continue;
            }
            float s0[8], s1[8];
            #pragma unroll
            for (int g = 0; g < 8; ++g) {
                u32 v = *(const u32*)&S[(g * 16 + nl) * SROW + m0];
                s0[g] = b2f((u16)(v & 0xffff));
                s1[g] = b2f((u16)(v >> 16));
            }
            #pragma unroll
            for (int h = 0; h < 8; ++h) {
                float o0 = th2b[h], o1 = th2b[h];
                #pragma unroll
                for (int g = 0; g < 8; ++g) {
                    const float w = th2w[h * 8 + g];   // SGPR
                    o0 += w * s0[g];
                    o1 += w * s1[g];
                }
                *(u32*)&S[(h * 16 + nl) * SROW + m0] =
                    (u32)f2b(o0) | ((u32)f2b(o1) << 16);
            }
        }
    }
    __syncthreads();

    // ---- phase 5: O = P @ V + vlocal, ReLU; O-tile staged in dead S ------
    {
        const int h = wid;
        const long vrow = (long)(b * NHD + h) * DVV;
        f32x4 acc[8];
        #pragma unroll
        for (int df = 0; df < 8; ++df) acc[df] = (f32x4){0.f, 0.f, 0.f, 0.f};
        for (int kc = 0; kc < 7; ++kc) {
            bf16x8 a0 = *(const bf16x8*)&S[(h * 16 + l15) * SROW + kc * 32 + lq8];
            __builtin_amdgcn_s_setprio(1);
            #pragma unroll
            for (int df = 0; df < 8; ++df) {
                bf16x8 bv = *(const bf16x8*)&vtT[(vrow + df * 16 + l15) * 224 + kc * 32 + lq8];
                acc[df] = __builtin_amdgcn_mfma_f32_16x16x32_bf16(a0, bv, acc[df], 0, 0, 0);
            }
            __builtin_amdgcn_s_setprio(0);
        }
        __syncthreads();   // all waves done reading P from S

        // stage O (bf16, +vlocal, ReLU) as S[16 rows][1024], quad-XOR swizzle
        const long lbase = (long)(b * NHD + h) * NSP;
        #pragma unroll
        for (int df = 0; df < 8; ++df) {
            const int d = df * 16 + col;
            #pragma unroll
            for (int r = 0; r < 4; ++r) {
                const int lm = quad * 4 + r;
                const int n = n0 + lm;
                const int nn = (n < NSP) ? n : (NSP - 1);  // clamp: unused if n>=NSP
                float v = acc[df][r] + b2f(vlt[(lbase + nn) * DVV + d]);
                const int kx = ((lm >> 2) & 3) << 4;
                S[lm * 1024 + ((h * 128 + d) ^ kx)] = f2b(fmaxf(v, 0.f));
            }
        }
    }
    __syncthreads();

    // coalesced ot store: 16 rows x 2048B; 4 chunks of 16B per thread,
    // 64 consecutive lanes = 1KB contiguous per instruction.
    {
        #pragma unroll
        for (int t = 0; t < 4; ++t) {
            const int ch = tid + t * 512;        // 0..2047
            const int lm = ch >> 7, seg = ch & 127;
            const int k2 = (lm >> 2) & 3;
            bf16x8 v = *(const bf16x8*)&S[lm * 1024 + ((seg ^ (k2 << 1)) << 3)];
            const int n = n0 + lm;
            if (n < NSP)
                *(bf16x8*)&ot[((long)(b * NSP + n)) * 1024 + seg * 8] = v;
        }
    }
}

// ---------------- K5: output projection (MFMA, BK=64), XCD-aware grid -----
// grid 600 (1-D): xcd=bid&7, q=bid>>3, o_t=q%3, m_t=xcd+8*(q/3).
// Epilogue: C (128oc x 64m f32) staged in the dead A+B LDS (32KB exactly),
// m-block XOR swizzle by quad=(oc>>2)&3; then coalesced f32 stores (each
// wave sweeps 64 consecutive m -> one 256B transaction).
__global__ __launch_bounds__(256) void k_proj(
    const u16* __restrict__ pwb, const u16* __restrict__ ot,
    const float* __restrict__ projb, float* __restrict__ outp)
{
    const int g = blockIdx.x;
    const int xcd = g & 7, q = g >> 3;
    const int o_t = q % 3, mgq = q / 3;
    const int m_t = xcd + 8 * mgq;
    if (m_t >= 196) return;
    __shared__ u16 LDS[16384];    // A(8192 u16) + B(4096 u16); reused: f32 C[128][64]
    u16* A_lds = LDS;
    u16* B_lds = LDS + 8192;
    const int tid = threadIdx.x, wid = tid >> 6, lane = tid & 63;
    const int lrow = lane >> 2, lcb = (lane & 3) << 4;
    const int m0 = m_t * 64, oc0 = o_t * 128;
    const int wm = (wid & 1) * 64, wn = (wid >> 1) * 32;
    const int l15 = lane & 15, lq8 = (lane >> 4) * 8;

    const char* gp[6];
    u16* lp[6];
    #pragma unroll
    for (int t = 0; t < 6; ++t) {
        int s = wid * 6 + t;            // 0..23
        int sub = s / 12, s12 = s - sub * 12;
        if (s12 < 8) {
            gp[t] = (const char*)pwb + (long)(oc0 + s12 * 16 + lrow) * 2048 + lcb + sub * 64;
            lp[t] = A_lds + sub * 4096 + s12 * 512;
        } else {
            gp[t] = (const char*)ot + (long)(m0 + (s12 - 8) * 16 + lrow) * 2048 + lcb + sub * 64;
            lp[t] = B_lds + sub * 2048 + (s12 - 8) * 512;
        }
    }

    f32x4 acc[4][2];
    #pragma unroll
    for (int i = 0; i < 4; ++i)
        #pragma unroll
        for (int j = 0; j < 2; ++j) acc[i][j] = (f32x4){0.f, 0.f, 0.f, 0.f};

    for (int kk = 0; kk < 16; ++kk) {
        #pragma unroll
        for (int t = 0; t < 6; ++t) { gld16(gp[t], lp[t]); gp[t] += 128; }
        __syncthreads();
        #pragma unroll
        for (int s = 0; s < 2; ++s) {
            bf16x8 af[4], bfr[2];
            #pragma unroll
            for (int i = 0; i < 4; ++i)
                af[i] = *(const bf16x8*)&A_lds[s * 4096 + (wm + i * 16 + l15) * 32 + lq8];
            #pragma unroll
            for (int j = 0; j < 2; ++j)
                bfr[j] = *(const bf16x8*)&B_lds[s * 2048 + (wn + j * 16 + l15) * 32 + lq8];
            #pragma unroll
            for (int i = 0; i < 4; ++i)
                #pragma unroll
                for (int j = 0; j < 2; ++j)
                    acc[i][j] = __builtin_amdgcn_mfma_f32_16x16x32_bf16(
                        af[i], bfr[j], acc[i][j], 0, 0, 0);
        }
        __syncthreads();
    }

    // stage C into LDS as f32[128][64], m-block swizzled by quad
    float* C = (float*)LDS;
    const int col = lane & 15, quad = lane >> 4;
    #pragma unroll
    for (int i = 0; i < 4; ++i) {
        #pragma unroll
        for (int j = 0; j < 2; ++j) {
            #pragma unroll
            for (int r = 0; r < 4; ++r) {
                const int oc_l = wm + i * 16 + quad * 4 + r;
                const int m_l  = wn + j * 16 + col;
                C[oc_l * 64 + (m_l ^ (quad << 4))] = acc[i][j][r];
            }
        }
    }
    __syncthreads();

    // coalesced store: wave sweeps 64 consecutive m of one oc row
    #pragma unroll
    for (int t = 0; t < 32; ++t) {
        const int e = tid + t * 256;
        const int oc_l = e >> 6, m_l = e & 63;
        const int swz = ((oc_l >> 2) & 3) << 4;
        float v = C[oc_l * 64 + (m_l ^ swz)] + projb[oc0 + oc_l];
        const int m_g = m0 + m_l;
        const int b = m_g / NSP, n = m_g - b * NSP;
        outp[((long)b * DIM + oc0 + oc_l) * NSP + n] = v;
    }
}

extern "C" void kernel_launch(void* const* d_in, const int* in_sizes, int n_in,
                              void* d_out, int out_size, void* d_ws, size_t ws_size,
                              hipStream_t stream) {
    const float* x        = (const float*)d_in[0];
    const float* qw       = (const float*)d_in[1];
    const float* qb       = (const float*)d_in[2];
    const float* kw       = (const float*)d_in[3];
    const float* kb       = (const float*)d_in[4];
    const float* vw       = (const float*)d_in[5];
    const float* vb       = (const float*)d_in[6];
    const float* vlw      = (const float*)d_in[7];
    const float* vlb      = (const float*)d_in[8];
    const float* th1w     = (const float*)d_in[9];
    const float* th1b     = (const float*)d_in[10];
    const float* th2w     = (const float*)d_in[11];
    const float* th2b     = (const float*)d_in[12];
    const float* projw    = (const float*)d_in[13];
    const float* projb    = (const float*)d_in[14];
    const float* bias_seg = (const float*)d_in[15];
    float* outp = (float*)d_out;

    // workspace layout (bytes, 16B aligned) -- identical to r14..r25
    char* w = (char*)d_ws;
    u16* xb      = (u16*)(w);                 //  9,633,792
    u16* wqkv    = (u16*)(w + 9633792);       //  1,179,648
    u16* pwb     = (u16*)(w + 10813440);      //    786,432
    u16* wpack   = (u16*)(w + 11599872);      //     18,432
    float* bmix  = (float*)(w + 11618304);    //      6,400
    u16* qt      = (u16*)(w + 11624704);      //  6,455,296 (12608 rows x 256)
    u16* kb16    = (u16*)(w + 18080000);      //  6,455,296
    u16* vt      = (u16*)(w + 24535296);      // 25,690,112
    u16* vtT     = (u16*)(w + 50225408);      // 29,360,128 (rows padded 224)
    u16* ot      = (u16*)(w + 79585536);      // 25,690,112
    u16* vlt     = (u16*)(w + 105275648);     // 25,690,112
    // total 130,965,760 B

    k_prep<<<dim3(6373), 256, 0, stream>>>(qw, kw, vw, projw, th1w, th1b,
                                           bias_seg, vlw, x, wqkv, pwb, bmix,
                                           wpack, xb);
    k_qkv<<<dim3(1248), 256, 0, stream>>>(xb, wqkv, qb, kb, vb, qt, kb16, vt);
    k_vtdw<<<dim3(512), 256, 0, stream>>>(vt, wpack, vlb, vtT, vlt);
    k_attn2<<<dim3(NSTRIP * 64), 512, 0, stream>>>(qt, kb16, vtT, vlt, th1w, th2w,
                                                   th2b, bmix, ot);
    k_proj<<<dim3(600), 256, 0, stream>>>(pwb, ot, projb, outp);
}

// Round 16
// 245.927 us; speedup vs baseline: 1.0766x; 1.0065x over previous
//
#include <hip/hip_runtime.h>
#include <hip/hip_bf16.h>

// Attention4D MI355X round 27 (r26 + vectorized k_prep x-transpose):
//  - r26 confirmed best: 247.5us, attn2 77.9us (setprio + line-perfect ot).
//  - k_prep x-transpose (5376 blocks, 38.5MB fp32): was 4 passes of scalar
//    4B loads + scalar 2B stores. Now 1 pass: one float4 load/thread
//    (16B; aligned since NSP=196%4==0 and n%4==0 -> n<196 => n+3<=195),
//    f32->bf16 at load into transposed u16 LDS tile (row stride 40; 8B
//    aligned reads, spread banks), one u16x4 store/thread. 4x fewer
//    load/store instructions (Guideline 13: hipcc never auto-vectorizes).
//  - Everything else byte-identical to r26: setprio attn2, coalesced
//    stores everywhere, XCD-aware grids, per-plane k_vtdw.
// B=64, DIM=384, N=196 (14x14), NH=8, KD=32, DV=128.

#define RES   14
#define NSP   196
#define NHD   8
#define KDIM  32
#define DVV   128
#define DIM   384
#define NQK   256
#define SCALE 0.17677669529663687f
#define SROW  224    // LDS score row stride (u16); 448B ≡ bank16: 2-way, free
#define PROW  136    // k_vtdw plane row stride (u16); 272B: 16B-aligned, +4 banks
#define NSTRIP 13    // 13 x 16 = 208 >= 196

typedef __attribute__((ext_vector_type(8))) short bf16x8;
typedef __attribute__((ext_vector_type(4))) float f32x4;
typedef __attribute__((ext_vector_type(4))) unsigned short u16x4;
typedef unsigned short u16;
typedef unsigned int u32;

__device__ __forceinline__ u16 f2b(float f) {
    union { __hip_bfloat16 b; u16 u; } c; c.b = __float2bfloat16(f); return c.u;
}
__device__ __forceinline__ float b2f(u16 u) {
    union { __hip_bfloat16 b; u16 u; } c; c.u = u; return __bfloat162float(c.b);
}

// async global->LDS, 16B per lane; LDS dest = wave-uniform base + lane*16
__device__ __forceinline__ void gld16(const void* g, void* l) {
    __builtin_amdgcn_global_load_lds(
        (__attribute__((address_space(1))) void*)(unsigned long long)(const char*)g,
        (__attribute__((address_space(3))) void*)l, 16, 0, 0);
}

// ---- 128x128 bf16 MFMA GEMM core, BK=64 (two BK=32 sub-tiles / barrier) ----
__device__ __forceinline__ void gemm128_bk64(const char* Aseg, long rbA,
                                             const char* Bseg, long rbB, int kIters,
                                             u16* A_lds, u16* B_lds, f32x4 acc[4][4])
{
    const int tid  = threadIdx.x;
    const int wid  = tid >> 6;
    const int lane = tid & 63;
    const int lrow = lane >> 2;
    const int lcb  = (lane & 3) << 4;
    const int r0   = wid * 32;
    const int wm   = (wid & 1) * 64, wn = (wid >> 1) * 64;
    const int l15  = lane & 15, lq8 = (lane >> 4) * 8;

    #pragma unroll
    for (int i = 0; i < 4; ++i)
        #pragma unroll
        for (int j = 0; j < 4; ++j) acc[i][j] = (f32x4){0.f, 0.f, 0.f, 0.f};

    const char* ap0 = Aseg + (long)(r0 + lrow) * rbA + lcb;
    const char* ap1 = ap0 + 16 * rbA;
    const char* bp0 = Bseg + (long)(r0 + lrow) * rbB + lcb;
    const char* bp1 = bp0 + 16 * rbB;
    u16* la0 = A_lds + r0 * 32;
    u16* la1 = la0 + 512;
    u16* lb0 = B_lds + r0 * 32;
    u16* lb1 = lb0 + 512;

    for (int kk = 0; kk < kIters; ++kk) {
        gld16(ap0, la0);        gld16(ap1, la1);
        gld16(bp0, lb0);        gld16(bp1, lb1);
        gld16(ap0 + 64, la0 + 4096); gld16(ap1 + 64, la1 + 4096);
        gld16(bp0 + 64, lb0 + 4096); gld16(bp1 + 64, lb1 + 4096);
        ap0 += 128; ap1 += 128; bp0 += 128; bp1 += 128;
        __syncthreads();
        #pragma unroll
        for (int s = 0; s < 2; ++s) {
            bf16x8 af[4], bfr[4];
            #pragma unroll
            for (int i = 0; i < 4; ++i)
                af[i] = *(const bf16x8*)&A_lds[s * 4096 + (wm + i * 16 + l15) * 32 + lq8];
            #pragma unroll
            for (int j = 0; j < 4; ++j)
                bfr[j] = *(const bf16x8*)&B_lds[s * 4096 + (wn + j * 16 + l15) * 32 + lq8];
            #pragma unroll
            for (int i = 0; i < 4; ++i)
                #pragma unroll
                for (int j = 0; j < 4; ++j)
                    acc[i][j] = __builtin_amdgcn_mfma_f32_16x16x32_bf16(
                        af[i], bfr[j], acc[i][j], 0, 0, 0);
        }
        __syncthreads();
    }
}

// ---------------- prep (merged): weights + biasmix + wpack + x transpose ----
// blocks [0,960): float4-vectorized weight conversions (4 elems/thread);
// 960: biasmix; [961,997): wpack; [997,6373): x transpose (vectorized).
__global__ __launch_bounds__(256) void k_prep(
    const float* __restrict__ qw, const float* __restrict__ kw,
    const float* __restrict__ vw, const float* __restrict__ pw,
    const float* __restrict__ th1w, const float* __restrict__ th1b,
    const float* __restrict__ bias_seg, const float* __restrict__ vlw,
    const float* __restrict__ x,
    u16* __restrict__ wqkv, u16* __restrict__ pwb, float* __restrict__ biasmix,
    u16* __restrict__ wpack, u16* __restrict__ xb)
{
    __shared__ float t[32][33];          // reused as u16 T[32][40] by transpose
    const int bid = blockIdx.x;
    if (bid < 960) {
        const int i = (bid * 256 + threadIdx.x) * 4;
        const float* src; u16* dst;
        if (i < 98304)       { src = qw + i;            dst = wqkv + i; }
        else if (i < 196608) { src = kw + (i - 98304);  dst = wqkv + i; }
        else if (i < 589824) { src = vw + (i - 196608); dst = wqkv + i; }
        else                 { src = pw + (i - 589824); dst = pwb + (i - 589824); }
        float4 v = *(const float4*)src;
        u16x4 o;
        o[0] = f2b(v.x); o[1] = f2b(v.y); o[2] = f2b(v.z); o[3] = f2b(v.w);
        *(u16x4*)dst = o;
    } else if (bid == 960) {
        for (int i2 = threadIdx.x; i2 < 8 * NSP; i2 += 256) {
            int hh = i2 / NSP, off = i2 - hh * NSP;
            float a = th1b[hh];
            #pragma unroll
            for (int g = 0; g < 8; ++g) a += th1w[hh * 8 + g] * bias_seg[g * NSP + off];
            biasmix[i2] = a;
        }
    } else if (bid < 997) {
        int i2 = (bid - 961) * 256 + threadIdx.x;   // 0..9215
        if (i2 < 9216) {
            int g = i2 / 72, r = i2 - g * 72;       // wpack[g*72+tap*8+t]=vlw[(g*8+t)*9+tap]
            int tap = r >> 3, tt = r & 7;
            wpack[i2] = f2b(vlw[(g * 8 + tt) * 9 + tap]);
        }
    } else {
        // x transpose, 32c x 32n tile, one pass: float4 load -> bf16 LDS
        // (transposed, row stride 40) -> u16x4 store.
        const int L = bid - 997;             // 5376 blocks
        const int b = L / 84, r = L - b * 84;
        const int c0 = (r / 7) * 32, n0 = (r % 7) * 32;
        u16* T = (u16*)t;                    // [32][40] u16 = 2560B <= 4224B

        const int c  = threadIdx.x >> 3;     // 0..31
        const int nq = threadIdx.x & 7;      // 0..7, n = n0 + nq*4
        const int n  = n0 + nq * 4;
        float4 v = {0.f, 0.f, 0.f, 0.f};
        if (n < NSP)                         // n%4==0, NSP%4==0 -> n+3 <= 195
            v = *(const float4*)&x[((long)b * DIM + c0 + c) * NSP + n];
        T[(nq * 4 + 0) * 40 + c] = f2b(v.x);
        T[(nq * 4 + 1) * 40 + c] = f2b(v.y);
        T[(nq * 4 + 2) * 40 + c] = f2b(v.z);
        T[(nq * 4 + 3) * 40 + c] = f2b(v.w);
        __syncthreads();
        const int nn = threadIdx.x >> 3;     // local n row
        const int cq = threadIdx.x & 7;      // c group of 4
        const int ng = n0 + nn;
        if (ng < NSP)
            *(u16x4*)&xb[((long)b * NSP + ng) * DIM + c0 + cq * 4] =
                *(const u16x4*)&T[nn * 40 + cq * 4];
    }
}

// ---------------- K1: QKV projection (MFMA, BK=64), XCD-aware grid --------
// grid 1248 (1-D): xcd=bid&7, q=bid>>3, oc_t=q%12, m_t=xcd+8*(q/12).
// Epilogue: C staged in LDS (bank-swizzled), then coalesced 16B stores.
__global__ __launch_bounds__(256) void k_qkv(
    const u16* __restrict__ xb, const u16* __restrict__ wqkv,
    const float* __restrict__ qb, const float* __restrict__ kb,
    const float* __restrict__ vb,
    u16* __restrict__ qt, u16* __restrict__ kb16, u16* __restrict__ vt)
{
    const int g = blockIdx.x;
    const int xcd = g & 7, q = g >> 3;
    const int oc_t = q % 12, mg = q / 12;
    const int m_t = xcd + 8 * mg;
    if (m_t >= 98) return;
    __shared__ u16 LDS[16384];          // A(8192) + B(8192); reused as 128x128 C
    const int m0 = m_t * 128, oc0 = oc_t * 128;
    f32x4 acc[4][4];
    gemm128_bk64((const char*)xb + (long)m0 * 768, 768,
                 (const char*)wqkv + (long)oc0 * 768, 768, 6,
                 LDS, LDS + 8192, acc);

    const int tid = threadIdx.x, wid = tid >> 6, lane = tid & 63;
    const int wm = (wid & 1) * 64, wn = (wid >> 1) * 64;
    const int col = lane & 15, quad = lane >> 4;

    // per-thread bias for the 4 j-columns (oc = oc0 + wn + j*16 + col)
    float bias[4];
    {
        const int ocb = oc0 + wn + col;
        if (oc0 < 256) {
            #pragma unroll
            for (int j = 0; j < 4; ++j) bias[j] = qb[ocb + j * 16];
        } else if (oc0 < 512) {
            #pragma unroll
            for (int j = 0; j < 4; ++j) bias[j] = kb[ocb - 256 + j * 16];
        } else {
            #pragma unroll
            for (int j = 0; j < 4; ++j) bias[j] = vb[ocb - 512 + j * 16];
        }
    }

    // stage C (bf16, +bias) into LDS; swizzle 32B col-group by (lm>>2)&3
    #pragma unroll
    for (int i = 0; i < 4; ++i) {
        #pragma unroll
        for (int r = 0; r < 4; ++r) {
            const int lm = wm + i * 16 + quad * 4 + r;
            const int kx = ((lm >> 2) & 3) << 4;
            #pragma unroll
            for (int j = 0; j < 4; ++j) {
                const int lc = wn + j * 16 + col;
                LDS[lm * 128 + (lc ^ kx)] = f2b(acc[i][j][r] + bias[j]);
            }
        }
    }
    __syncthreads();

    // coalesced store: 2048 16B chunks; lanes 0-15 = one 256B row segment
    #pragma unroll
    for (int t2 = 0; t2 < 8; ++t2) {
        const int ch = tid + t2 * 256;
        const int lm = ch >> 4, seg = ch & 15;
        const int k2 = (lm >> 2) & 3;
        bf16x8 v = *(const bf16x8*)&LDS[lm * 128 + ((seg ^ (k2 << 1)) << 3)];
        const int m = m0 + lm;
        u16* dst;
        if (oc0 < 256) {
            dst = &qt[(long)m * 256 + oc0 + seg * 8];
        } else if (oc0 < 512) {
            dst = &kb16[(long)m * 256 + (oc0 - 256) + seg * 8];
        } else {
            const int b = m / NSP, n = m - b * NSP;
            dst = &vt[(((long)b * NHD + ((oc0 - 512) >> 7)) * NSP + n) * DVV + seg * 8];
        }
        *(bf16x8*)dst = v;
    }
}

// ---------------- K2: per-plane vtT transpose + dwconv from LDS ----------
__global__ __launch_bounds__(256) void k_vtdw(
    const u16* __restrict__ vt, const u16* __restrict__ wpack,
    const float* __restrict__ vlb,
    u16* __restrict__ vtT, u16* __restrict__ vlt)
{
    __shared__ u16 P[NSP * PROW];
    const int bh = blockIdx.x;
    const int tid = threadIdx.x;
    const int h = bh & 7;
    const long plane = (long)bh * NSP * DVV;

    // stage: 13 iters x 16 n-rows; thread (nrow=tid>>4, dseg=tid&15)
    {
        const int dseg = tid & 15, nrow = tid >> 4;
        #pragma unroll
        for (int i = 0; i < 13; ++i) {
            int n = i * 16 + nrow;
            if (n < NSP)
                *(bf16x8*)&P[n * PROW + dseg * 8] =
                    *(const bf16x8*)&vt[plane + (long)n * DVV + dseg * 8];
        }
    }
    __syncthreads();

    // (a) transpose out: thread (d=tid>>1, hh=tid&1); per 32-n block the
    // two halves (hh*16) are line-adjacent -> 32 transactions per inst.
    {
        const int d = tid >> 1, hh = tid & 1;
        const long orow = ((long)bh * DVV + d) * 224;
        #pragma unroll
        for (int nb = 0; nb < 7; ++nb) {
            const int n0s = nb * 32 + hh * 16;
            u16 tmp[16];
            #pragma unroll
            for (int j = 0; j < 16; ++j) {
                int n = n0s + j;
                tmp[j] = (n < NSP) ? P[n * PROW + d] : (u16)0;
            }
            *(bf16x8*)&vtT[orow + n0s]     = *(const bf16x8*)&tmp[0];
            *(bf16x8*)&vtT[orow + n0s + 8] = *(const bf16x8*)&tmp[8];
        }
    }

    // (b) dwconv from LDS (no barrier needed: P is read-only now)
    {
        const int dg = tid & 15, nl = tid >> 4;
        const int d0 = dg * 8;
        const u16* wb = wpack + (h * 16 + dg) * 72;
        bf16x8 wv[9];
        #pragma unroll
        for (int tap = 0; tap < 9; ++tap) wv[tap] = *(const bf16x8*)&wb[tap * 8];
        float bias[8];
        #pragma unroll
        for (int k2 = 0; k2 < 8; ++k2) bias[k2] = vlb[h * DVV + d0 + k2];
        #pragma unroll
        for (int c = 0; c < 13; ++c) {
            const int n = c * 16 + nl;
            if (n >= NSP) break;
            const int y = n / RES, xx = n - y * RES;
            float acc[8];
            #pragma unroll
            for (int k2 = 0; k2 < 8; ++k2) acc[k2] = bias[k2];
            #pragma unroll
            for (int dy = -1; dy <= 1; ++dy) {
                int yy = y + dy;
                if (yy < 0 || yy >= RES) continue;
                #pragma unroll
                for (int dx = -1; dx <= 1; ++dx) {
                    int xn = xx + dx;
                    if (xn < 0 || xn >= RES) continue;
                    int tap = (dy + 1) * 3 + dx + 1;
                    bf16x8 v = *(const bf16x8*)&P[(yy * RES + xn) * PROW + d0];
                    #pragma unroll
                    for (int k2 = 0; k2 < 8; ++k2)
                        acc[k2] += b2f((u16)wv[tap][k2]) * b2f((u16)v[k2]);
                }
            }
            bf16x8 r;
            #pragma unroll
            for (int k2 = 0; k2 < 8; ++k2) r[k2] = (short)f2b(acc[k2]);
            *(bf16x8*)&vlt[plane + (long)n * DVV + d0] = r;
        }
    }
}

// ---------------- K3: fused attention middle (EXACT r26) ------------------
// grid 832: xcd = L&7, b = xcd + 8*(wq/13), strip = wq%13, n0 = strip*16.
// S: 128 rows x 224 u16 = 57,344 B + bmS 3,136 B -> 2 blocks/CU (16 waves).
__global__ __launch_bounds__(512, 2) void k_attn2(
    const u16* __restrict__ qt, const u16* __restrict__ kb16,
    const u16* __restrict__ vtT, const u16* __restrict__ vlt,
    const float* __restrict__ th1w, const float* __restrict__ th2w,
    const float* __restrict__ th2b, const float* __restrict__ biasmix,
    u16* __restrict__ ot)
{
    __shared__ u16 S[128 * SROW];
    __shared__ u16 bmS[8 * NSP];
    const int tid = threadIdx.x;
    const int L  = blockIdx.x;
    const int wq = L >> 3;
    const int b  = (L & 7) + ((wq / NSTRIP) << 3);
    const int n0 = (wq % NSTRIP) * 16;
    const int wid = tid >> 6, lane = tid & 63;
    const int l15 = lane & 15, lq8 = (lane >> 4) * 8;
    const int quad = lane >> 4, col = lane & 15;

    for (int i = tid; i < 8 * NSP; i += 512) bmS[i] = f2b(biasmix[i]);
    __syncthreads();

    // ---- phase 1: scores (MFMA) + th1 mix + bias, fused in registers ----
    {
        const long qrow = ((long)(b * NSP) + n0 + l15) * NQK;
        bf16x8 af[8];
        #pragma unroll
        for (int g = 0; g < 8; ++g)
            af[g] = *(const bf16x8*)&qt[qrow + g * 32 + lq8];
        #pragma unroll
        for (int jj = 0; jj < 2; ++jj) {
            const int j = wid + jj * 8;
            if (j >= 13) break;              // j=13 strip is garbage (phase 4 zeroes)
            const long krow = ((long)(b * NSP) + j * 16 + l15) * NQK;
            f32x4 t[8];
            __builtin_amdgcn_s_setprio(1);
            #pragma unroll
            for (int g = 0; g < 8; ++g) {
                bf16x8 bv = *(const bf16x8*)&kb16[krow + g * 32 + lq8];
                t[g] = __builtin_amdgcn_mfma_f32_16x16x32_bf16(
                    af[g], bv, (f32x4){0.f, 0.f, 0.f, 0.f}, 0, 0, 0);
            }
            __builtin_amdgcn_s_setprio(0);
            const int m = j * 16 + col;
            const int ym = m / RES, xm = m - ym * RES;
            int offr[4];
            #pragma unroll
            for (int r = 0; r < 4; ++r) {
                int gn = n0 + quad * 4 + r;
                int yn = gn / RES, xn = gn - yn * RES;
                int off = abs(yn - ym) * RES + abs(xn - xm);
                offr[r] = (off > 195) ? 195 : off;   // garbage rows/cols only
            }
            #pragma unroll
            for (int h = 0; h < 8; ++h) {
                float o[4];
                #pragma unroll
                for (int r = 0; r < 4; ++r) o[r] = b2f(bmS[h * NSP + offr[r]]);
                #pragma unroll
                for (int g = 0; g < 8; ++g) {
                    const float w = th1w[h * 8 + g] * SCALE;  // SGPR
                    #pragma unroll
                    for (int r = 0; r < 4; ++r) o[r] += w * t[g][r];
                }
                #pragma unroll
                for (int r = 0; r < 4; ++r)
                    S[(h * 16 + quad * 4 + r) * SROW + m] = f2b(o[r]);
            }
        }
    }
    __syncthreads();

    // ---- phase 3: softmax, 4 rows per wave concurrently (16-lane groups) ----
    {
        const int c = lane & 15, rg = lane >> 4;
        #pragma unroll
        for (int it = 0; it < 4; ++it) {
            u16* row = &S[(wid * 16 + it * 4 + rg) * SROW];
            float v[13];
            #pragma unroll
            for (int k = 0; k < 12; ++k) v[k] = b2f(row[c + 16 * k]);
            v[12] = (c < 4) ? b2f(row[192 + c]) : -1e30f;
            float mx = v[0];
            #pragma unroll
            for (int k = 1; k < 13; ++k) mx = fmaxf(mx, v[k]);
            #pragma unroll
            for (int o = 1; o < 16; o <<= 1) mx = fmaxf(mx, __shfl_xor(mx, o));
            float sum = 0.f;
            #pragma unroll
            for (int k = 0; k < 13; ++k) { v[k] = __expf(v[k] - mx); sum += v[k]; }
            if (c >= 4) sum -= v[12];   // garbage lane contribution
            #pragma unroll
            for (int o = 1; o < 16; o <<= 1) sum += __shfl_xor(sum, o);
            float inv = 1.0f / sum;
            #pragma unroll
            for (int k = 0; k < 12; ++k) row[c + 16 * k] = f2b(v[k] * inv);
            if (c < 4) row[192 + c] = f2b(v[12] * inv);
        }
    }
    __syncthreads();

    // ---- phase 4: th2 mix (+bias), zero pad m in [196,224), paired u32 ----
    {
        for (int p = tid; p < 16 * 112; p += 512) {
            const int nl = p / 112, kp = p - nl * 112;
            const int m0 = kp * 2;
            if (m0 >= NSP) {
                #pragma unroll
                for (int h = 0; h < 8; ++h)
                    *(u32*)&S[(h * 16 + nl) * SROW + m0] = 0u;
                continue;
            }
            float s0[8], s1[8];
            #pragma unroll
            for (int g = 0; g < 8; ++g) {
                u32 v = *(const u32*)&S[(g * 16 + nl) * SROW + m0];
                s0[g] = b2f((u16)(v & 0xffff));
                s1[g] = b2f((u16)(v >> 16));
            }
            #pragma unroll
            for (int h = 0; h < 8; ++h) {
                float o0 = th2b[h], o1 = th2b[h];
                #pragma unroll
                for (int g = 0; g < 8; ++g) {
                    const float w = th2w[h * 8 + g];   // SGPR
                    o0 += w * s0[g];
                    o1 += w * s1[g];
                }
                *(u32*)&S[(h * 16 + nl) * SROW + m0] =
                    (u32)f2b(o0) | ((u32)f2b(o1) << 16);
            }
        }
    }
    __syncthreads();

    // ---- phase 5: O = P @ V + vlocal, ReLU; O-tile staged in dead S ------
    {
        const int h = wid;
        const long vrow = (long)(b * NHD + h) * DVV;
        f32x4 acc[8];
        #pragma unroll
        for (int df = 0; df < 8; ++df) acc[df] = (f32x4){0.f, 0.f, 0.f, 0.f};
        for (int kc = 0; kc < 7; ++kc) {
            bf16x8 a0 = *(const bf16x8*)&S[(h * 16 + l15) * SROW + kc * 32 + lq8];
            __builtin_amdgcn_s_setprio(1);
            #pragma unroll
            for (int df = 0; df < 8; ++df) {
                bf16x8 bv = *(const bf16x8*)&vtT[(vrow + df * 16 + l15) * 224 + kc * 32 + lq8];
                acc[df] = __builtin_amdgcn_mfma_f32_16x16x32_bf16(a0, bv, acc[df], 0, 0, 0);
            }
            __builtin_amdgcn_s_setprio(0);
        }
        __syncthreads();   // all waves done reading P from S

        // stage O (bf16, +vlocal, ReLU) as S[16 rows][1024], quad-XOR swizzle
        const long lbase = (long)(b * NHD + h) * NSP;
        #pragma unroll
        for (int df = 0; df < 8; ++df) {
            const int d = df * 16 + col;
            #pragma unroll
            for (int r = 0; r < 4; ++r) {
                const int lm = quad * 4 + r;
                const int n = n0 + lm;
                const int nn = (n < NSP) ? n : (NSP - 1);  // clamp: unused if n>=NSP
                float v = acc[df][r] + b2f(vlt[(lbase + nn) * DVV + d]);
                const int kx = ((lm >> 2) & 3) << 4;
                S[lm * 1024 + ((h * 128 + d) ^ kx)] = f2b(fmaxf(v, 0.f));
            }
        }
    }
    __syncthreads();

    // coalesced ot store: 16 rows x 2048B; 4 chunks of 16B per thread,
    // 64 consecutive lanes = 1KB contiguous per instruction.
    {
        #pragma unroll
        for (int t = 0; t < 4; ++t) {
            const int ch = tid + t * 512;        // 0..2047
            const int lm = ch >> 7, seg = ch & 127;
            const int k2 = (lm >> 2) & 3;
            bf16x8 v = *(const bf16x8*)&S[lm * 1024 + ((seg ^ (k2 << 1)) << 3)];
            const int n = n0 + lm;
            if (n < NSP)
                *(bf16x8*)&ot[((long)(b * NSP + n)) * 1024 + seg * 8] = v;
        }
    }
}

// ---------------- K5: output projection (MFMA, BK=64), XCD-aware grid -----
__global__ __launch_bounds__(256) void k_proj(
    const u16* __restrict__ pwb, const u16* __restrict__ ot,
    const float* __restrict__ projb, float* __restrict__ outp)
{
    const int g = blockIdx.x;
    const int xcd = g & 7, q = g >> 3;
    const int o_t = q % 3, mgq = q / 3;
    const int m_t = xcd + 8 * mgq;
    if (m_t >= 196) return;
    __shared__ u16 LDS[16384];    // A(8192 u16) + B(4096 u16); reused: f32 C[128][64]
    u16* A_lds = LDS;
    u16* B_lds = LDS + 8192;
    const int tid = threadIdx.x, wid = tid >> 6, lane = tid & 63;
    const int lrow = lane >> 2, lcb = (lane & 3) << 4;
    const int m0 = m_t * 64, oc0 = o_t * 128;
    const int wm = (wid & 1) * 64, wn = (wid >> 1) * 32;
    const int l15 = lane & 15, lq8 = (lane >> 4) * 8;

    const char* gp[6];
    u16* lp[6];
    #pragma unroll
    for (int t = 0; t < 6; ++t) {
        int s = wid * 6 + t;            // 0..23
        int sub = s / 12, s12 = s - sub * 12;
        if (s12 < 8) {
            gp[t] = (const char*)pwb + (long)(oc0 + s12 * 16 + lrow) * 2048 + lcb + sub * 64;
            lp[t] = A_lds + sub * 4096 + s12 * 512;
        } else {
            gp[t] = (const char*)ot + (long)(m0 + (s12 - 8) * 16 + lrow) * 2048 + lcb + sub * 64;
            lp[t] = B_lds + sub * 2048 + (s12 - 8) * 512;
        }
    }

    f32x4 acc[4][2];
    #pragma unroll
    for (int i = 0; i < 4; ++i)
        #pragma unroll
        for (int j = 0; j < 2; ++j) acc[i][j] = (f32x4){0.f, 0.f, 0.f, 0.f};

    for (int kk = 0; kk < 16; ++kk) {
        #pragma unroll
        for (int t = 0; t < 6; ++t) { gld16(gp[t], lp[t]); gp[t] += 128; }
        __syncthreads();
        #pragma unroll
        for (int s = 0; s < 2; ++s) {
            bf16x8 af[4], bfr[2];
            #pragma unroll
            for (int i = 0; i < 4; ++i)
                af[i] = *(const bf16x8*)&A_lds[s * 4096 + (wm + i * 16 + l15) * 32 + lq8];
            #pragma unroll
            for (int j = 0; j < 2; ++j)
                bfr[j] = *(const bf16x8*)&B_lds[s * 2048 + (wn + j * 16 + l15) * 32 + lq8];
            #pragma unroll
            for (int i = 0; i < 4; ++i)
                #pragma unroll
                for (int j = 0; j < 2; ++j)
                    acc[i][j] = __builtin_amdgcn_mfma_f32_16x16x32_bf16(
                        af[i], bfr[j], acc[i][j], 0, 0, 0);
        }
        __syncthreads();
    }

    // stage C into LDS as f32[128][64], m-block swizzled by quad
    float* C = (float*)LDS;
    const int col = lane & 15, quad = lane >> 4;
    #pragma unroll
    for (int i = 0; i < 4; ++i) {
        #pragma unroll
        for (int j = 0; j < 2; ++j) {
            #pragma unroll
            for (int r = 0; r < 4; ++r) {
                const int oc_l = wm + i * 16 + quad * 4 + r;
                const int m_l  = wn + j * 16 + col;
                C[oc_l * 64 + (m_l ^ (quad << 4))] = acc[i][j][r];
            }
        }
    }
    __syncthreads();

    // coalesced store: wave sweeps 64 consecutive m of one oc row
    #pragma unroll
    for (int t = 0; t < 32; ++t) {
        const int e = tid + t * 256;
        const int oc_l = e >> 6, m_l = e & 63;
        const int swz = ((oc_l >> 2) & 3) << 4;
        float v = C[oc_l * 64 + (m_l ^ swz)] + projb[oc0 + oc_l];
        const int m_g = m0 + m_l;
        const int b = m_g / NSP, n = m_g - b * NSP;
        outp[((long)b * DIM + oc0 + oc_l) * NSP + n] = v;
    }
}

extern "C" void kernel_launch(void* const* d_in, const int* in_sizes, int n_in,
                              void* d_out, int out_size, void* d_ws, size_t ws_size,
                              hipStream_t stream) {
    const float* x        = (const float*)d_in[0];
    const float* qw       = (const float*)d_in[1];
    const float* qb       = (const float*)d_in[2];
    const float* kw       = (const float*)d_in[3];
    const float* kb       = (const float*)d_in[4];
    const float* vw       = (const float*)d_in[5];
    const float* vb       = (const float*)d_in[6];
    const float* vlw      = (const float*)d_in[7];
    const float* vlb      = (const float*)d_in[8];
    const float* th1w     = (const float*)d_in[9];
    const float* th1b     = (const float*)d_in[10];
    const float* th2w     = (const float*)d_in[11];
    const float* th2b     = (const float*)d_in[12];
    const float* projw    = (const float*)d_in[13];
    const float* projb    = (const float*)d_in[14];
    const float* bias_seg = (const float*)d_in[15];
    float* outp = (float*)d_out;

    // workspace layout (bytes, 16B aligned) -- identical to r14..r26
    char* w = (char*)d_ws;
    u16* xb      = (u16*)(w);                 //  9,633,792
    u16* wqkv    = (u16*)(w + 9633792);       //  1,179,648
    u16* pwb     = (u16*)(w + 10813440);      //    786,432
    u16* wpack   = (u16*)(w + 11599872);      //     18,432
    float* bmix  = (float*)(w + 11618304);    //      6,400
    u16* qt      = (u16*)(w + 11624704);      //  6,455,296 (12608 rows x 256)
    u16* kb16    = (u16*)(w + 18080000);      //  6,455,296
    u16* vt      = (u16*)(w + 24535296);      // 25,690,112
    u16* vtT     = (u16*)(w + 50225408);      // 29,360,128 (rows padded 224)
    u16* ot      = (u16*)(w + 79585536);      // 25,690,112
    u16* vlt     = (u16*)(w + 105275648);     // 25,690,112
    // total 130,965,760 B

    k_prep<<<dim3(6373), 256, 0, stream>>>(qw, kw, vw, projw, th1w, th1b,
                                           bias_seg, vlw, x, wqkv, pwb, bmix,
                                           wpack, xb);
    k_qkv<<<dim3(1248), 256, 0, stream>>>(xb, wqkv, qb, kb, vb, qt, kb16, vt);
    k_vtdw<<<dim3(512), 256, 0, stream>>>(vt, wpack, vlb, vtT, vlt);
    k_attn2<<<dim3(NSTRIP * 64), 512, 0, stream>>>(qt, kb16, vtT, vlt, th1w, th2w,
                                                   th2b, bmix, ot);
    k_proj<<<dim3(600), 256, 0, stream>>>(pwb, ot, projb, outp);
}